// Round 1
// baseline (317.672 us; speedup 1.0000x reference)
//
#include <hip/hip_runtime.h>

// SkeletalPool: out[b, j, c, t] = 0.5f * (x[b, idx0(j), c, t] + x[b, idx1(j), c, t])
//   x:   [32, 31, 64, 4096] fp32
//   out: [32, 16, 64, 4096] fp32
//   idx0(j) = j==0 ? 0 : 2j-1 ; idx1(j) = 2j
//
// Memory-bound: 1.04 GB in + 0.54 GB out, every input element read once.
// float4 loads/stores (16 B/lane), grid-stride loop, bit-op index decompose
// (inner (c,t) plane = 64*4096 floats = 65536 float4s = 2^16).

__global__ __launch_bounds__(256) void skel_pool_kernel(
    const float4* __restrict__ x, float4* __restrict__ out, int total4) {
    int tid = blockIdx.x * blockDim.x + threadIdx.x;
    int stride = gridDim.x * blockDim.x;
    for (int v = tid; v < total4; v += stride) {
        int plane = v >> 16;      // = b*16 + j   (out plane index)
        int rem   = v & 0xFFFF;   // float4 offset within the (c,t) plane
        int b     = plane >> 4;
        int j     = plane & 15;
        int j1    = j << 1;                 // 2j
        int j0    = j ? (j1 - 1) : 0;       // max(2j-1, 0)
        int ibase = b * 31;                 // input plane base (in planes)
        float4 a = x[((ibase + j0) << 16) + rem];
        float4 c = x[((ibase + j1) << 16) + rem];
        float4 r;
        r.x = (a.x + c.x) * 0.5f;
        r.y = (a.y + c.y) * 0.5f;
        r.z = (a.z + c.z) * 0.5f;
        r.w = (a.w + c.w) * 0.5f;
        out[v] = r;
    }
}

extern "C" void kernel_launch(void* const* d_in, const int* in_sizes, int n_in,
                              void* d_out, int out_size, void* d_ws, size_t ws_size,
                              hipStream_t stream) {
    const float4* x = (const float4*)d_in[0];
    float4* out = (float4*)d_out;
    int total4 = out_size / 4;  // 134,217,728 / 4 = 33,554,432 float4s
    const int block = 256;
    int blocks = (total4 + block - 1) / block;
    if (blocks > 2048) blocks = 2048;  // grid-stride the rest (G11)
    skel_pool_kernel<<<blocks, block, 0, stream>>>(x, out, total4);
}

// Round 3
// 313.310 us; speedup vs baseline: 1.0139x; 1.0139x over previous
//
#include <hip/hip_runtime.h>

// SkeletalPool: out[b, j, c, t] = 0.5f * (x[b, idx0(j), c, t] + x[b, idx1(j), c, t])
//   x:   [32, 31, 64, 4096] fp32 (1.04 GB)
//   out: [32, 16, 64, 4096] fp32 (0.54 GB)
//   idx0(j) = j==0 ? 0 : 2j-1 ; idx1(j) = 2j
//
// Memory-bound streaming op, every input element read exactly once (plane 0
// twice, same thread). R3: unroll x4 for MLP (8 loads in flight) +
// non-temporal hints via clang ext-vector f32x4 (HIP float4 is a struct,
// __builtin_nontemporal_* requires native vector types).

typedef float f32x4 __attribute__((ext_vector_type(4)));

#define UNROLL 4

__global__ __launch_bounds__(256) void skel_pool_kernel(
    const f32x4* __restrict__ x, f32x4* __restrict__ out, int total4) {
    int tid = blockIdx.x * blockDim.x + threadIdx.x;
    int stride = gridDim.x * blockDim.x;

    int v = tid;
    // Main unrolled body: 8 NT loads issued before 4 NT stores per iter.
    for (; v + (UNROLL - 1) * stride < total4; v += UNROLL * stride) {
        f32x4 r[UNROLL];
#pragma unroll
        for (int u = 0; u < UNROLL; ++u) {
            int vv    = v + u * stride;
            int plane = vv >> 16;      // b*16 + j
            int rem   = vv & 0xFFFF;   // f32x4 offset in (c,t) plane (2^16)
            int b     = plane >> 4;
            int j     = plane & 15;
            int j1    = j << 1;                // 2j
            int j0    = j1 - (j != 0);         // max(2j-1, 0)
            int ib    = b * 31;
            f32x4 a = __builtin_nontemporal_load(&x[((ib + j0) << 16) + rem]);
            f32x4 c = __builtin_nontemporal_load(&x[((ib + j1) << 16) + rem]);
            r[u] = (a + c) * 0.5f;
        }
#pragma unroll
        for (int u = 0; u < UNROLL; ++u)
            __builtin_nontemporal_store(r[u], &out[v + u * stride]);
    }
    // Tail (not taken for this shape: total4 = 2^25, stride = 2^19, 64 iters)
    for (; v < total4; v += stride) {
        int plane = v >> 16;
        int rem   = v & 0xFFFF;
        int b     = plane >> 4;
        int j     = plane & 15;
        int j1    = j << 1;
        int j0    = j1 - (j != 0);
        int ib    = b * 31;
        f32x4 a = __builtin_nontemporal_load(&x[((ib + j0) << 16) + rem]);
        f32x4 c = __builtin_nontemporal_load(&x[((ib + j1) << 16) + rem]);
        f32x4 r = (a + c) * 0.5f;
        __builtin_nontemporal_store(r, &out[v]);
    }
}

extern "C" void kernel_launch(void* const* d_in, const int* in_sizes, int n_in,
                              void* d_out, int out_size, void* d_ws, size_t ws_size,
                              hipStream_t stream) {
    const f32x4* x = (const f32x4*)d_in[0];
    f32x4* out = (f32x4*)d_out;
    int total4 = out_size / 4;  // 134,217,728 / 4 = 2^25 f32x4s
    const int block = 256;
    int blocks = (total4 + block - 1) / block;
    if (blocks > 2048) blocks = 2048;  // 8 waves/SIMD, grid-stride the rest
    skel_pool_kernel<<<blocks, block, 0, stream>>>(x, out, total4);
}

// Round 4
// 294.852 us; speedup vs baseline: 1.0774x; 1.0626x over previous
//
#include <hip/hip_runtime.h>

// SkeletalPool: out[b, j, c, t] = 0.5f * (x[b, idx0(j), c, t] + x[b, idx1(j), c, t])
//   x:   [32, 31, 64, 4096] fp32 (1.04 GB)
//   out: [32, 16, 64, 4096] fp32 (0.54 GB)
//   idx0(j) = j==0 ? 0 : 2j-1 ; idx1(j) = 2j
//
// R4 theory: R1/R3 stuck at 5.0 TB/s because each wave burst was only 1KB and
// unroll strided 8MB apart -> DRAM row thrash. New mapping: each wave owns a
// contiguous 4KB chunk per plane (lane*16B + u*1KB, compile-time offsets).
// Per-chunk index decompose (chunks never cross the 1MiB plane boundary).

typedef float f32x4 __attribute__((ext_vector_type(4)));

#define U 4  // float4s per lane per chunk; wave chunk = 64 lanes * U * 16B = 4KB

__global__ __launch_bounds__(256) void skel_pool_kernel(
    const f32x4* __restrict__ x, f32x4* __restrict__ out,
    int nchunks, int nwaves) {
    int gtid = blockIdx.x * blockDim.x + threadIdx.x;
    int wave = gtid >> 6;
    int lane = gtid & 63;

    for (int k = wave; k < nchunks; k += nwaves) {
        int plane = k >> 8;          // out plane = b*16 + j (256 chunks/plane)
        int remb  = ((k & 255) << 8) + lane;  // float4 offset in plane
        int b     = plane >> 4;
        int j     = plane & 15;
        int j1    = j << 1;               // 2j
        int j0    = j1 - (j != 0);        // max(2j-1, 0)
        int ib    = b * 31;

        const f32x4* pa = x + ((ib + j0) << 16) + remb;
        const f32x4* pc = x + ((ib + j1) << 16) + remb;
        f32x4*       po = out + (plane << 16) + remb;

        f32x4 a[U], c[U];
#pragma unroll
        for (int u = 0; u < U; ++u) a[u] = pa[u * 64];   // offset:u*1KB
#pragma unroll
        for (int u = 0; u < U; ++u) c[u] = pc[u * 64];
#pragma unroll
        for (int u = 0; u < U; ++u)
            __builtin_nontemporal_store((a[u] + c[u]) * 0.5f, po + u * 64);
    }
}

extern "C" void kernel_launch(void* const* d_in, const int* in_sizes, int n_in,
                              void* d_out, int out_size, void* d_ws, size_t ws_size,
                              hipStream_t stream) {
    const f32x4* x = (const f32x4*)d_in[0];
    f32x4* out = (f32x4*)d_out;
    int total4  = out_size / 4;        // 2^25 f32x4
    int nchunks = total4 >> 8;         // 256 f32x4 (4KB) per chunk = 131072
    const int block = 256;
    int blocks = 2048;                 // 8192 waves -> 16 chunks per wave
    int nwaves = blocks * (block / 64);
    skel_pool_kernel<<<blocks, block, 0, stream>>>(x, out, nchunks, nwaves);
}

// Round 5
// 280.901 us; speedup vs baseline: 1.1309x; 1.0497x over previous
//
#include <hip/hip_runtime.h>

// SkeletalPool: out[b, j, c, t] = 0.5f * (x[b, idx0(j), c, t] + x[b, idx1(j), c, t])
//   x:   [32, 31, 64, 4096] fp32 (1.04 GB)
//   out: [32, 16, 64, 4096] fp32 (0.54 GB)
//   idx0(j) = j==0 ? 0 : 2j-1 ; idx1(j) = 2j
//
// R5: R4's wave-chunking (+6%) showed DRAM row locality is the lever.
// Double per-wave burst (U=8 -> 8KB contiguous per plane per iteration,
// 16 NT loads in flight) while halving wave count (1024 blocks -> 4096
// waves) to keep the aggregate concurrent footprint at ~32MB output.

typedef float f32x4 __attribute__((ext_vector_type(4)));

#define U 8  // float4s per lane per chunk; wave chunk = 64*U*16B = 8KB/plane

__global__ __launch_bounds__(256) void skel_pool_kernel(
    const f32x4* __restrict__ x, f32x4* __restrict__ out,
    int nchunks, int nwaves) {
    int gtid = blockIdx.x * blockDim.x + threadIdx.x;
    int wave = gtid >> 6;
    int lane = gtid & 63;

    for (int k = wave; k < nchunks; k += nwaves) {
        int plane = k >> 7;                   // 128 chunks per 1MiB plane
        int remb  = ((k & 127) << 9) + lane;  // float4 offset in plane
        int b     = plane >> 4;
        int j     = plane & 15;
        int j1    = j << 1;               // 2j
        int j0    = j1 - (j != 0);        // max(2j-1, 0)
        int ib    = b * 31;

        const f32x4* pa = x + ((ib + j0) << 16) + remb;
        const f32x4* pc = x + ((ib + j1) << 16) + remb;
        f32x4*       po = out + (plane << 16) + remb;

        f32x4 a[U], c[U];
#pragma unroll
        for (int u = 0; u < U; ++u) a[u] = __builtin_nontemporal_load(pa + u * 64);
#pragma unroll
        for (int u = 0; u < U; ++u) c[u] = __builtin_nontemporal_load(pc + u * 64);
#pragma unroll
        for (int u = 0; u < U; ++u)
            __builtin_nontemporal_store((a[u] + c[u]) * 0.5f, po + u * 64);
    }
}

extern "C" void kernel_launch(void* const* d_in, const int* in_sizes, int n_in,
                              void* d_out, int out_size, void* d_ws, size_t ws_size,
                              hipStream_t stream) {
    const f32x4* x = (const f32x4*)d_in[0];
    f32x4* out = (f32x4*)d_out;
    int total4  = out_size / 4;          // 2^25 f32x4
    int nchunks = total4 >> 9;           // 512 f32x4 (8KB) per chunk = 65536
    const int block = 256;
    int blocks = 1024;                   // 4096 waves -> 16 chunks per wave
    int nwaves = blocks * (block / 64);
    skel_pool_kernel<<<blocks, block, 0, stream>>>(x, out, nchunks, nwaves);
}